// Round 10
// baseline (123.027 us; speedup 1.0000x reference)
//
#include <hip/hip_runtime.h>

// msg[b,o,n] = sum_d We[o,d]*e_vw[b,d,n] + sum_d Ww[o,d]*h_w[b,d,n] + be[o]+bw[o]
// B=128, D=768, N=256. Fused GEMM per batch: M=768, N=256, K=1536.
// Tile 192x256, BK=64, 512 thr = 8 waves (2m x 4n), wave tile 96x64.
// THIS ROUND: A-operand DIRECT from global in MFMA-fragment order
// (Wfrag, prep kernel, L2-resident 2.4 MB) -> LDS holds ONLY B.
// LDS/step: 216 KB -> 96 KB. One lgkm-only barrier per K-step.

#define DD   768
#define NCOL 256
#define KTOT 1536
#define BM   192
#define BN   256
#define BK   64
#define NIT  24

typedef __bf16 bf16;
typedef __attribute__((ext_vector_type(8))) __bf16 bf16x8;
typedef __attribute__((ext_vector_type(4))) float f32x4;
typedef __attribute__((ext_vector_type(4))) unsigned int u32x4;

// 128B rows (B tile). XOR row bits into 16B-slot bits: <=2-way per quarter.
__device__ __forceinline__ int swz(int row, int kb) {
  return row * 128 + (kb ^ (((row ^ (row >> 3)) & 7) << 4));
}

// ---- prep: Wfrag[mt][T][s][M][lane] = 16B chunk (8 bf16, k-contiguous) ----
// Fragment mapping (verified rounds 1-9): lane l of fragment (M,s) holds
// rows M*16 + (l&15), k = T*64 + s*32 + (l>>4)*8 .. +7.
__global__ void prep_w(const float* __restrict__ We, const float* __restrict__ Ww,
                       unsigned short* __restrict__ Wfrag) {
  int i = blockIdx.x * blockDim.x + threadIdx.x;  // 147456 chunks
  int lane = i & 63;
  int r = i >> 6;
  int M = r % 12;  r /= 12;
  int s = r & 1;   r >>= 1;
  int T = r % 24;
  int mt = r / 24;
  int o = mt * 192 + M * 16 + (lane & 15);
  int k = T * 64 + s * 32 + (lane >> 4) * 8;
  const float* src = (k < DD) ? (We + (size_t)o * DD + k)
                              : (Ww + (size_t)o * DD + (k - DD));
  f32x4 v0 = *(const f32x4*)src;
  f32x4 v1 = *(const f32x4*)(src + 4);
  union { bf16 h8[8]; u32x4 q; } u;
  u.h8[0]=(bf16)v0[0]; u.h8[1]=(bf16)v0[1]; u.h8[2]=(bf16)v0[2]; u.h8[3]=(bf16)v0[3];
  u.h8[4]=(bf16)v1[0]; u.h8[5]=(bf16)v1[1]; u.h8[6]=(bf16)v1[2]; u.h8[7]=(bf16)v1[3];
  *(u32x4*)(Wfrag + (size_t)i * 8) = u.q;
}

__global__ __launch_bounds__(512, 2)
void msg_kernel(const float* __restrict__ h_w, const float* __restrict__ e_vw,
                const unsigned short* __restrict__ Wfrag,
                const float* __restrict__ be, const float* __restrict__ bw,
                float* __restrict__ out) {
  // B dbuf: 2 x 32 KB; bias at 65536
  __shared__ __align__(16) unsigned char smem[2 * 32768 + 768];
  float* bias_s = (float*)(smem + 65536);

  const int tid = threadIdx.x;
  // XCD map: xcd = p&7 owns batches xcd*16..+15; 4 m-blocks of a batch are
  // consecutive slots on the same XCD -> X[b] L2 reuse.
  const int p = blockIdx.x;
  const int slot = p >> 3;
  const int bb = (p & 7) * 16 + (slot >> 2);
  const int mt = slot & 3;
  const int bm0 = mt * 192;

  if (tid < 192) bias_s[tid] = be[bm0 + tid] + bw[bm0 + tid];

  // ---- B staging: thread = (nq = tid&63 -> 4 cols, kk = tid>>6 -> 8 k) ----
  const int nq = tid & 63, kk = tid >> 6;
  const size_t xofs = (size_t)bb * DD * NCOL + (size_t)(kk * 8) * NCOL + nq * 4;
  const float* pE = e_vw + xofs;
  const float* pH = h_w + xofs;
  int wBo[4];
  #pragma unroll
  for (int j = 0; j < 4; ++j) wBo[j] = swz(4 * nq + j, kk * 16);

  f32x4 bR[8];   // B prefetch (fp32, 4 cols x 8 k)

  auto issueB = [&](int T) {
    const float* q = (T < 12) ? (pE + (size_t)T * BK * NCOL)
                              : (pH + (size_t)(T - 12) * BK * NCOL);
    #pragma unroll
    for (int i = 0; i < 8; ++i) bR[i] = *(const f32x4*)(q + (size_t)i * NCOL);
  };
  auto storeB = [&](int buf) {
    unsigned char* base = smem + buf * 32768;
    #pragma unroll
    for (int j = 0; j < 4; ++j) {
      union { bf16 h8[8]; u32x4 q; } u;
      #pragma unroll
      for (int i = 0; i < 8; ++i) u.h8[i] = (bf16)bR[i][j];
      *(u32x4*)(base + wBo[j]) = u.q;
    }
  };

  // ---- compute map: 8 waves = 2m x 4n, wave tile 96x64 ----
  const int lane = tid & 63, wid = tid >> 6;
  const int wm = wid >> 2, wn = wid & 3;
  const int lr = lane & 15, qk = (lane >> 4) * 16;
  const int wm6 = wm * 6;
  f32x4 acc[6][4] = {};

  // A-fragment base: Wfrag + mt block + lane; addr(T,s,m) adds chunk index.
  const unsigned short* pW = Wfrag + ((size_t)mt * 24 * 2 * 12 * 64 + (size_t)lane) * 8;
  bf16x8 af[12];   // af[s*6+m] = fragment (slice s, m)

  auto loadA = [&](int T) {
    #pragma unroll
    for (int s = 0; s < 2; ++s)
      #pragma unroll
      for (int m = 0; m < 6; ++m)
        af[s * 6 + m] =
            *(const bf16x8*)(pW + (size_t)(((T * 2 + s) * 12 + wm6 + m) * 64) * 8);
  };

  // ---- prologue: stage B tile 0, prefetch B tile 1, A frags for step 0 ----
  issueB(0);
  storeB(0);
  issueB(1);
  loadA(0);
  asm volatile("s_waitcnt lgkmcnt(0)" ::: "memory");
  __builtin_amdgcn_s_barrier();

  // ---- main loop: one lgkm-only barrier per K-step ----
  for (int t = 0; t < NIT; ++t) {
    const int c = t & 1;
    const unsigned char* bB = smem + c * 32768;
    bf16x8 bfv0[4], bfv1[4];

    // B fragment reads (8 x b128)
    #pragma unroll
    for (int n = 0; n < 4; ++n)
      bfv0[n] = *(const bf16x8*)(bB + swz(wn * 64 + n * 16 + lr, qk));
    #pragma unroll
    for (int n = 0; n < 4; ++n)
      bfv1[n] = *(const bf16x8*)(bB + swz(wn * 64 + n * 16 + lr, 64 + qk));

    // k-slice 0 MFMA cluster (af[0..5] x bfv0) — counted vmcnt gates af
    #pragma unroll
    for (int m = 0; m < 6; ++m)
      #pragma unroll
      for (int n = 0; n < 4; ++n)
        acc[m][n] = __builtin_amdgcn_mfma_f32_16x16x32_bf16(af[m], bfv0[n], acc[m][n], 0, 0, 0);

    // stage B tile t+1 (consumes bR), THEN refill bR with tile t+2 (WAR order)
    if (t < NIT - 1) storeB(c ^ 1);
    if (t < NIT - 2) issueB(t + 2);

    // k-slice 1 MFMA cluster (af[6..11] x bfv1)
    #pragma unroll
    for (int m = 0; m < 6; ++m)
      #pragma unroll
      for (int n = 0; n < 4; ++n)
        acc[m][n] = __builtin_amdgcn_mfma_f32_16x16x32_bf16(af[6 + m], bfv1[n], acc[m][n], 0, 0, 0);

    // A frags for step t+1: issued after their consumers, ~barrier+ds_reads
    // of latency cover before first use (L2 hit ~250 cy)
    if (t < NIT - 1) loadA(t + 1);

    // single sync point for B dbuf
    asm volatile("s_waitcnt lgkmcnt(0)" ::: "memory");
    __builtin_amdgcn_s_barrier();
  }

  // ---- epilogue: bias + store. C/D: col=lane&15, row=(lane>>4)*4+reg ----
  float* po = out + (size_t)bb * DD * NCOL;
  const int g4 = (lane >> 4) * 4;
  #pragma unroll
  for (int m = 0; m < 6; ++m) {
    const int r0 = wm * 96 + m * 16 + g4;
    #pragma unroll
    for (int n = 0; n < 4; ++n) {
      const int col = wn * 64 + n * 16 + lr;
      #pragma unroll
      for (int j = 0; j < 4; ++j)
        po[(size_t)(bm0 + r0 + j) * NCOL + col] = acc[m][n][j] + bias_s[r0 + j];
    }
  }
}

extern "C" void kernel_launch(void* const* d_in, const int* in_sizes, int n_in,
                              void* d_out, int out_size, void* d_ws, size_t ws_size,
                              hipStream_t stream) {
  // inputs: 0:h_v(unused) 1:h_w 2:e_vw 3:We 4:be 5:Ww 6:bw
  const float* h_w  = (const float*)d_in[1];
  const float* e_vw = (const float*)d_in[2];
  const float* We   = (const float*)d_in[3];
  const float* be   = (const float*)d_in[4];
  const float* Ww   = (const float*)d_in[5];
  const float* bw   = (const float*)d_in[6];
  float* out = (float*)d_out;
  unsigned short* Wfrag = (unsigned short*)d_ws;  // 147456 x 16B = 2.36 MB

  prep_w<<<dim3(576), 256, 0, stream>>>(We, Ww, Wfrag);
  msg_kernel<<<dim3(512), 512, 0, stream>>>(h_w, e_vw, Wfrag, be, bw, out);
}